// Round 5
// baseline (238.154 us; speedup 1.0000x reference)
//
#include <hip/hip_runtime.h>
#include <hip/hip_cooperative_groups.h>

namespace cg = cooperative_groups;

#define IN_F 256
#define HID 512
#define OUT_F 2048
#define N_HEADS 8
#define BATCH 4096
#define MT 40  // BATCH/128 + N_HEADS worst-case M-tiles

typedef __bf16 bf16_t;
typedef bf16_t bf16x8 __attribute__((ext_vector_type(8)));
typedef float f32x4 __attribute__((ext_vector_type(4)));

typedef __attribute__((address_space(1))) const unsigned int gu32;
typedef __attribute__((address_space(3))) unsigned int lu32;

__device__ inline unsigned short f2bf(float f) {
  union { float f; unsigned u; } v; v.f = f;
  unsigned u = v.u;
  unsigned r = (u + 0x7FFFu + ((u >> 16) & 1u)) >> 16;  // RNE
  return (unsigned short)r;
}

// map flat M-tile index -> (head, row0, rows), BM=128
__device__ __forceinline__ bool map_tile(const int* offsets, int my,
                                         int& head, int& row0, int& rows) {
  head = -1;
  int acc_t = 0;
#pragma unroll
  for (int h = 0; h < N_HEADS; ++h) {
    int o0 = offsets[h], o1 = offsets[h + 1];
    int cnt = o1 - o0;
    int t = (cnt + 127) >> 7;
    if (head < 0 && my < acc_t + t) {
      head = h;
      int lt = my - acc_t;
      row0 = o0 + lt * 128;
      rows = min(128, cnt - lt * 128);
    }
    acc_t += t;
  }
  return head >= 0;
}

// ---------------- phase bodies (shared by mega + fallback kernels) ----------

__device__ __forceinline__ void bucket_body(const int* __restrict__ idxh,
                                            int* __restrict__ order,
                                            int* __restrict__ offsets,
                                            char* smem, int tid) {
  int* cnt = (int*)smem;
  int* basep = cnt + 8;
  int* cur = basep + 9;
  if (tid < N_HEADS) cnt[tid] = 0;
  __syncthreads();
  for (int i = tid; i < BATCH; i += 256) atomicAdd(&cnt[idxh[i]], 1);
  __syncthreads();
  if (tid == 0) {
    int a = 0;
#pragma unroll
    for (int h = 0; h < N_HEADS; ++h) { basep[h] = a; cur[h] = a; a += cnt[h]; }
    basep[N_HEADS] = a;
  }
  __syncthreads();
  if (tid < N_HEADS + 1) offsets[tid] = basep[tid];
  for (int i = tid; i < BATCH; i += 256) {
    int pos = atomicAdd(&cur[idxh[i]], 1);
    order[pos] = i;
  }
}

// one 64x64 transpose tile, t in [0, 2304)
__device__ __forceinline__ void transpose_body(const float* __restrict__ W1,
                                               unsigned short* __restrict__ W1t,
                                               const float* __restrict__ W2,
                                               unsigned short* __restrict__ W2t,
                                               char* smem, int tid, int t) {
  float (*tile)[65] = (float(*)[65])smem;
  int c = tid & 63, r0 = tid >> 6;
  const float* W; unsigned short* Wt; int K, N, b, nt, kt;
  if (t < 256) { W = W1; Wt = W1t; K = IN_F; N = HID; b = t; nt = 8; kt = 4; }
  else { W = W2; Wt = W2t; K = HID; N = OUT_F; b = t - 256; nt = 32; kt = 8; }
  int per_head = nt * kt;
  int h = b / per_head, rem = b % per_head;
  int n0 = (rem % nt) * 64, k0 = (rem / nt) * 64;
  const float* Wh = W + (size_t)h * K * N;
  unsigned short* Wth = Wt + (size_t)h * K * N;
  for (int rr = r0; rr < 64; rr += 4)
    tile[rr][c] = Wh[(size_t)(k0 + rr) * N + n0 + c];
  __syncthreads();
  for (int rr = r0; rr < 64; rr += 4)
    Wth[(size_t)(n0 + rr) * K + k0 + c] = f2bf(tile[c][rr]);
  __syncthreads();
}

// one 128x128 GEMM1 tile: A from X (fp32, via order) on the fly, B = W1t
__device__ __forceinline__ void gemm1_tile(const float* __restrict__ X,
                                           const int* __restrict__ order,
                                           const unsigned short* __restrict__ W1t,
                                           const float* __restrict__ b1,
                                           unsigned short* __restrict__ Hb,
                                           int head, int row0, int rows, int n0,
                                           char* smem, int tid) {
  unsigned short* As = (unsigned short*)smem;
  unsigned short* Bs = (unsigned short*)(smem + 8192);
  int wave = tid >> 6, lane = tid & 63;
  int q = lane >> 4, l16 = lane & 15;
  int w_m = wave >> 1, w_n = wave & 1;
  int ldrow = lane >> 2, ldcol = (lane & 3) * 8;
  int c0 = wave * 2, c1 = c0 + 1;
  int arow = tid >> 1, acolh = (tid & 1) * 16;

  const unsigned short* Bh = W1t + (size_t)head * HID * IN_F;
  const unsigned short* bp0 = Bh + (size_t)(n0 + c0 * 16 + ldrow) * IN_F + ldcol;
  const unsigned short* bp1 = Bh + (size_t)(n0 + c1 * 16 + ldrow) * IN_F + ldcol;
  unsigned short* lB0 = Bs + c0 * 512;
  unsigned short* lB1 = Bs + c1 * 512;
  int src = order[row0 + min(arow, rows - 1)];
  const float* xrow = X + (size_t)src * IN_F + acolh;
  unsigned short* aw = As + arow * 32 + acolh;

  f32x4 acc[4][4];
#pragma unroll
  for (int i = 0; i < 4; ++i)
#pragma unroll
    for (int j = 0; j < 4; ++j) acc[i][j] = (f32x4){0.f, 0.f, 0.f, 0.f};

  for (int k0 = 0; k0 < IN_F; k0 += 32) {
    __builtin_amdgcn_global_load_lds((gu32*)bp0, (lu32*)lB0, 16, 0, 0);
    __builtin_amdgcn_global_load_lds((gu32*)bp1, (lu32*)lB1, 16, 0, 0);
    bp0 += 32; bp1 += 32;
    const float4* xp = (const float4*)(xrow + k0);
    float4 f0 = xp[0], f1 = xp[1], f2 = xp[2], f3 = xp[3];
    uint4 o0, o1;
    o0.x = (unsigned)f2bf(f0.x) | ((unsigned)f2bf(f0.y) << 16);
    o0.y = (unsigned)f2bf(f0.z) | ((unsigned)f2bf(f0.w) << 16);
    o0.z = (unsigned)f2bf(f1.x) | ((unsigned)f2bf(f1.y) << 16);
    o0.w = (unsigned)f2bf(f1.z) | ((unsigned)f2bf(f1.w) << 16);
    o1.x = (unsigned)f2bf(f2.x) | ((unsigned)f2bf(f2.y) << 16);
    o1.y = (unsigned)f2bf(f2.z) | ((unsigned)f2bf(f2.w) << 16);
    o1.z = (unsigned)f2bf(f3.x) | ((unsigned)f2bf(f3.y) << 16);
    o1.w = (unsigned)f2bf(f3.z) | ((unsigned)f2bf(f3.w) << 16);
    *(uint4*)aw = o0;
    *(uint4*)(aw + 8) = o1;
    __syncthreads();

    bf16x8 af[4], bfr[4];
#pragma unroll
    for (int i = 0; i < 4; ++i) {
      af[i] = *(const bf16x8*)(As + (w_m * 64 + i * 16 + l16) * 32 + q * 8);
      bfr[i] = *(const bf16x8*)(Bs + (w_n * 64 + i * 16 + l16) * 32 + q * 8);
    }
#pragma unroll
    for (int mi = 0; mi < 4; ++mi)
#pragma unroll
      for (int ni = 0; ni < 4; ++ni)
        acc[mi][ni] = __builtin_amdgcn_mfma_f32_16x16x32_bf16(af[mi], bfr[ni], acc[mi][ni], 0, 0, 0);
    __syncthreads();
  }

  float bval[4];
#pragma unroll
  for (int ni = 0; ni < 4; ++ni)
    bval[ni] = b1[(size_t)head * HID + n0 + w_n * 64 + ni * 16 + l16];
#pragma unroll
  for (int mi = 0; mi < 4; ++mi) {
#pragma unroll
    for (int r = 0; r < 4; ++r) {
      int m = w_m * 64 + mi * 16 + q * 4 + r;
      if (m < rows) {
        int p = row0 + m;
#pragma unroll
        for (int ni = 0; ni < 4; ++ni) {
          int n = n0 + w_n * 64 + ni * 16 + l16;
          float v = acc[mi][ni][r] + bval[ni];
          v = v > 0.f ? v : 0.f;
          Hb[(size_t)p * HID + n] = f2bf(v);
        }
      }
    }
  }
}

// one 128x128 GEMM2 tile: A = Hb (bf16), B = W2t, fp32 scatter to out
__device__ __forceinline__ void gemm2_tile(const unsigned short* __restrict__ Hb,
                                           const unsigned short* __restrict__ W2t,
                                           const float* __restrict__ b2,
                                           const int* __restrict__ order,
                                           float* __restrict__ out,
                                           int head, int row0, int rows, int n0,
                                           char* smem, int tid) {
  unsigned short* As = (unsigned short*)smem;
  unsigned short* Bs = (unsigned short*)(smem + 8192);
  int wave = tid >> 6, lane = tid & 63;
  int q = lane >> 4, l16 = lane & 15;
  int w_m = wave >> 1, w_n = wave & 1;
  int ldrow = lane >> 2, ldcol = (lane & 3) * 8;
  int c0 = wave * 2, c1 = c0 + 1;

  const unsigned short* Bh = W2t + (size_t)head * (size_t)OUT_F * HID;
  int ar0 = row0 + min(c0 * 16 + ldrow, rows - 1);
  int ar1 = row0 + min(c1 * 16 + ldrow, rows - 1);
  const unsigned short* ap0 = Hb + (size_t)ar0 * HID + ldcol;
  const unsigned short* ap1 = Hb + (size_t)ar1 * HID + ldcol;
  const unsigned short* bp0 = Bh + (size_t)(n0 + c0 * 16 + ldrow) * HID + ldcol;
  const unsigned short* bp1 = Bh + (size_t)(n0 + c1 * 16 + ldrow) * HID + ldcol;
  unsigned short* lA0 = As + c0 * 512;
  unsigned short* lA1 = As + c1 * 512;
  unsigned short* lB0 = Bs + c0 * 512;
  unsigned short* lB1 = Bs + c1 * 512;

  f32x4 acc[4][4];
#pragma unroll
  for (int i = 0; i < 4; ++i)
#pragma unroll
    for (int j = 0; j < 4; ++j) acc[i][j] = (f32x4){0.f, 0.f, 0.f, 0.f};

  for (int k0 = 0; k0 < HID; k0 += 32) {
    __builtin_amdgcn_global_load_lds((gu32*)ap0, (lu32*)lA0, 16, 0, 0);
    __builtin_amdgcn_global_load_lds((gu32*)ap1, (lu32*)lA1, 16, 0, 0);
    __builtin_amdgcn_global_load_lds((gu32*)bp0, (lu32*)lB0, 16, 0, 0);
    __builtin_amdgcn_global_load_lds((gu32*)bp1, (lu32*)lB1, 16, 0, 0);
    ap0 += 32; ap1 += 32; bp0 += 32; bp1 += 32;
    __syncthreads();

    bf16x8 af[4], bfr[4];
#pragma unroll
    for (int i = 0; i < 4; ++i) {
      af[i] = *(const bf16x8*)(As + (w_m * 64 + i * 16 + l16) * 32 + q * 8);
      bfr[i] = *(const bf16x8*)(Bs + (w_n * 64 + i * 16 + l16) * 32 + q * 8);
    }
#pragma unroll
    for (int mi = 0; mi < 4; ++mi)
#pragma unroll
      for (int ni = 0; ni < 4; ++ni)
        acc[mi][ni] = __builtin_amdgcn_mfma_f32_16x16x32_bf16(af[mi], bfr[ni], acc[mi][ni], 0, 0, 0);
    __syncthreads();
  }

  float bval[4];
#pragma unroll
  for (int ni = 0; ni < 4; ++ni)
    bval[ni] = b2[(size_t)head * OUT_F + n0 + w_n * 64 + ni * 16 + l16];
#pragma unroll
  for (int mi = 0; mi < 4; ++mi) {
#pragma unroll
    for (int r = 0; r < 4; ++r) {
      int m = w_m * 64 + mi * 16 + q * 4 + r;
      if (m < rows) {
        int rg = order[row0 + m];
#pragma unroll
        for (int ni = 0; ni < 4; ++ni) {
          int n = n0 + w_n * 64 + ni * 16 + l16;
          out[(size_t)rg * OUT_F + n] = acc[mi][ni][r] + bval[ni];
        }
      }
    }
  }
}

// ---------------- cooperative mega-kernel -----------------------------------
__global__ __launch_bounds__(256, 2) void mega_kernel(
    const float* __restrict__ X, const int* __restrict__ idxh,
    const float* __restrict__ W1, const float* __restrict__ b1,
    const float* __restrict__ W2, const float* __restrict__ b2,
    float* __restrict__ out,
    int* order, int* offsets,
    unsigned short* __restrict__ W1t, unsigned short* __restrict__ W2t,
    unsigned short* __restrict__ Hb) {
  __shared__ __align__(16) char smem[16640];
  cg::grid_group grid = cg::this_grid();
  int tid = threadIdx.x;

  if (blockIdx.x == 0) {
    bucket_body(idxh, order, offsets, smem, tid);
  } else {
    for (int t = (int)blockIdx.x - 1; t < 2304; t += (int)gridDim.x - 1)
      transpose_body(W1, W1t, W2, W2t, smem, tid, t);
  }
  grid.sync();

  for (int t = blockIdx.x; t < MT * 4; t += gridDim.x) {
    int my = t >> 2, nx = t & 3;
    int head, row0, rows;
    if (!map_tile(offsets, my, head, row0, rows)) continue;
    gemm1_tile(X, order, W1t, b1, Hb, head, row0, rows, nx * 128, smem, tid);
  }
  grid.sync();

  for (int t = blockIdx.x; t < MT * 16; t += gridDim.x) {
    int my = t >> 4, nx = t & 15;
    int head, row0, rows;
    if (!map_tile(offsets, my, head, row0, rows)) continue;
    gemm2_tile(Hb, W2t, b2, order, out, head, row0, rows, nx * 128, smem, tid);
  }
}

// ---------------- fallback kernels (3 dispatches) ---------------------------
__global__ __launch_bounds__(256) void prep_kernel(const int* __restrict__ idxh,
                                                   int* order, int* offsets,
                                                   const float* __restrict__ W1,
                                                   unsigned short* __restrict__ W1t,
                                                   const float* __restrict__ W2,
                                                   unsigned short* __restrict__ W2t) {
  __shared__ __align__(16) char smem[16640];
  int tid = threadIdx.x;
  if (blockIdx.x == 0) {
    bucket_body(idxh, order, offsets, smem, tid);
  } else {
    for (int t = (int)blockIdx.x - 1; t < 2304; t += (int)gridDim.x - 1)
      transpose_body(W1, W1t, W2, W2t, smem, tid, t);
  }
}

__global__ __launch_bounds__(256) void gemm1_kernel(const float* __restrict__ X,
                                                    const int* __restrict__ order,
                                                    const int* __restrict__ offsets,
                                                    const unsigned short* __restrict__ W1t,
                                                    const float* __restrict__ b1,
                                                    unsigned short* __restrict__ Hb) {
  __shared__ __align__(16) char smem[16384];
  int head, row0, rows;
  if (!map_tile(offsets, blockIdx.y, head, row0, rows)) return;
  gemm1_tile(X, order, W1t, b1, Hb, head, row0, rows, blockIdx.x * 128, smem, threadIdx.x);
}

__global__ __launch_bounds__(256) void gemm2_kernel(const unsigned short* __restrict__ Hb,
                                                    const unsigned short* __restrict__ W2t,
                                                    const float* __restrict__ b2,
                                                    const int* __restrict__ offsets,
                                                    const int* __restrict__ order,
                                                    float* __restrict__ out) {
  __shared__ __align__(16) char smem[16384];
  int head, row0, rows;
  if (!map_tile(offsets, blockIdx.y, head, row0, rows)) return;
  gemm2_tile(Hb, W2t, b2, order, out, head, row0, rows, blockIdx.x * 128, smem, threadIdx.x);
}

extern "C" void kernel_launch(void* const* d_in, const int* in_sizes, int n_in,
                              void* d_out, int out_size, void* d_ws, size_t ws_size,
                              hipStream_t stream) {
  const float* X = (const float*)d_in[0];
  const int* idxh = (const int*)d_in[1];
  const float* W1 = (const float*)d_in[2];
  const float* b1 = (const float*)d_in[3];
  const float* W2 = (const float*)d_in[4];
  const float* b2 = (const float*)d_in[5];
  float* out = (float*)d_out;

  char* ws = (char*)d_ws;
  int* order = (int*)ws;                     ws += (size_t)BATCH * 4;
  int* offsets = (int*)ws;                   ws += 64;
  unsigned short* W1t = (unsigned short*)ws; ws += (size_t)N_HEADS * IN_F * HID * 2;
  unsigned short* W2t = (unsigned short*)ws; ws += (size_t)N_HEADS * HID * OUT_F * 2;
  unsigned short* Hb = (unsigned short*)ws;  ws += (size_t)BATCH * HID * 2;

  bool coop_ok = false;
  int nb = 0;
  if (hipOccupancyMaxActiveBlocksPerMultiprocessor(&nb, (const void*)mega_kernel,
                                                   256, 0) == hipSuccess && nb >= 1) {
    int grid = nb * 256;
    if (grid > 512) grid = 512;
    void* args[] = {(void*)&X, (void*)&idxh, (void*)&W1, (void*)&b1,
                    (void*)&W2, (void*)&b2, (void*)&out,
                    (void*)&order, (void*)&offsets,
                    (void*)&W1t, (void*)&W2t, (void*)&Hb};
    if (hipLaunchCooperativeKernel((void*)mega_kernel, dim3(grid), dim3(256),
                                   (void**)args, 0, stream) == hipSuccess)
      coop_ok = true;
  }

  if (!coop_ok) {
    prep_kernel<<<dim3(512), dim3(256), 0, stream>>>(idxh, order, offsets, W1, W1t, W2, W2t);
    gemm1_kernel<<<dim3(HID / 128, MT), dim3(256), 0, stream>>>(X, order, offsets, W1t, b1, Hb);
    gemm2_kernel<<<dim3(OUT_F / 128, MT), dim3(256), 0, stream>>>(Hb, W2t, b2, offsets, order, out);
  }
}

// Round 6
// 137.952 us; speedup vs baseline: 1.7263x; 1.7263x over previous
//
#include <hip/hip_runtime.h>

#define IN_F 256
#define HID 512
#define OUT_F 2048
#define N_HEADS 8
#define BATCH 4096
#define MT 40  // BATCH/128 + N_HEADS worst-case M-tiles

typedef __bf16 bf16_t;
typedef bf16_t bf16x8 __attribute__((ext_vector_type(8)));
typedef float f32x4 __attribute__((ext_vector_type(4)));

typedef __attribute__((address_space(1))) const unsigned int gu32;
typedef __attribute__((address_space(3))) unsigned int lu32;

__device__ inline unsigned short f2bf(float f) {
  union { float f; unsigned u; } v; v.f = f;
  unsigned u = v.u;
  unsigned r = (u + 0x7FFFu + ((u >> 16) & 1u)) >> 16;  // RNE
  return (unsigned short)r;
}

// map flat M-tile index -> (head, row0, rows), BM=128
__device__ __forceinline__ bool map_tile(const int* offsets, int my,
                                         int& head, int& row0, int& rows) {
  head = -1;
  int acc_t = 0;
#pragma unroll
  for (int h = 0; h < N_HEADS; ++h) {
    int o0 = offsets[h], o1 = offsets[h + 1];
    int cnt = o1 - o0;
    int t = (cnt + 127) >> 7;
    if (head < 0 && my < acc_t + t) {
      head = h;
      int lt = my - acc_t;
      row0 = o0 + lt * 128;
      rows = min(128, cnt - lt * 128);
    }
    acc_t += t;
  }
  return head >= 0;
}

__device__ __forceinline__ void bucket_body(const int* __restrict__ idxh,
                                            int* __restrict__ order,
                                            int* __restrict__ offsets,
                                            char* smem, int tid) {
  int* cnt = (int*)smem;
  int* basep = cnt + 8;
  int* cur = basep + 9;
  if (tid < N_HEADS) cnt[tid] = 0;
  __syncthreads();
  for (int i = tid; i < BATCH; i += 256) atomicAdd(&cnt[idxh[i]], 1);
  __syncthreads();
  if (tid == 0) {
    int a = 0;
#pragma unroll
    for (int h = 0; h < N_HEADS; ++h) { basep[h] = a; cur[h] = a; a += cnt[h]; }
    basep[N_HEADS] = a;
  }
  __syncthreads();
  if (tid < N_HEADS + 1) offsets[tid] = basep[tid];
  for (int i = tid; i < BATCH; i += 256) {
    int pos = atomicAdd(&cur[idxh[i]], 1);
    order[pos] = i;
  }
}

// one 64x64 transpose tile of W[h] ([K][N] fp32) -> Wt[h] ([N][K] bf16)
__device__ __forceinline__ void transpose_one(const float* __restrict__ W,
                                              unsigned short* __restrict__ Wt,
                                              int K, int N, int b, int nt,
                                              char* smem, int tid) {
  float (*tile)[65] = (float(*)[65])smem;
  int c = tid & 63, r0 = tid >> 6;
  int per_head = nt * (K / 64);
  int h = b / per_head, rem = b % per_head;
  int n0 = (rem % nt) * 64, k0 = (rem / nt) * 64;
  const float* Wh = W + (size_t)h * K * N;
  unsigned short* Wth = Wt + (size_t)h * K * N;
  for (int rr = r0; rr < 64; rr += 4)
    tile[rr][c] = Wh[(size_t)(k0 + rr) * N + n0 + c];
  __syncthreads();
  for (int rr = r0; rr < 64; rr += 4)
    Wth[(size_t)(n0 + rr) * K + k0 + c] = f2bf(tile[c][rr]);
}

// one 128x128 GEMM1 tile: A from X (fp32, via order) on the fly, B = W1t
__device__ __forceinline__ void gemm1_tile(const float* __restrict__ X,
                                           const int* __restrict__ order,
                                           const unsigned short* __restrict__ W1t,
                                           const float* __restrict__ b1,
                                           unsigned short* __restrict__ Hb,
                                           int head, int row0, int rows, int n0,
                                           char* smem, int tid) {
  unsigned short* As = (unsigned short*)smem;
  unsigned short* Bs = (unsigned short*)(smem + 8192);
  int wave = tid >> 6, lane = tid & 63;
  int q = lane >> 4, l16 = lane & 15;
  int w_m = wave >> 1, w_n = wave & 1;
  int ldrow = lane >> 2, ldcol = (lane & 3) * 8;
  int c0 = wave * 2, c1 = c0 + 1;
  int arow = tid >> 1, acolh = (tid & 1) * 16;

  const unsigned short* Bh = W1t + (size_t)head * HID * IN_F;
  const unsigned short* bp0 = Bh + (size_t)(n0 + c0 * 16 + ldrow) * IN_F + ldcol;
  const unsigned short* bp1 = Bh + (size_t)(n0 + c1 * 16 + ldrow) * IN_F + ldcol;
  unsigned short* lB0 = Bs + c0 * 512;
  unsigned short* lB1 = Bs + c1 * 512;
  int src = order[row0 + min(arow, rows - 1)];
  const float* xrow = X + (size_t)src * IN_F + acolh;
  unsigned short* aw = As + arow * 32 + acolh;

  f32x4 acc[4][4];
#pragma unroll
  for (int i = 0; i < 4; ++i)
#pragma unroll
    for (int j = 0; j < 4; ++j) acc[i][j] = (f32x4){0.f, 0.f, 0.f, 0.f};

  for (int k0 = 0; k0 < IN_F; k0 += 32) {
    __builtin_amdgcn_global_load_lds((gu32*)bp0, (lu32*)lB0, 16, 0, 0);
    __builtin_amdgcn_global_load_lds((gu32*)bp1, (lu32*)lB1, 16, 0, 0);
    bp0 += 32; bp1 += 32;
    const float4* xp = (const float4*)(xrow + k0);
    float4 f0 = xp[0], f1 = xp[1], f2 = xp[2], f3 = xp[3];
    uint4 o0, o1;
    o0.x = (unsigned)f2bf(f0.x) | ((unsigned)f2bf(f0.y) << 16);
    o0.y = (unsigned)f2bf(f0.z) | ((unsigned)f2bf(f0.w) << 16);
    o0.z = (unsigned)f2bf(f1.x) | ((unsigned)f2bf(f1.y) << 16);
    o0.w = (unsigned)f2bf(f1.z) | ((unsigned)f2bf(f1.w) << 16);
    o1.x = (unsigned)f2bf(f2.x) | ((unsigned)f2bf(f2.y) << 16);
    o1.y = (unsigned)f2bf(f2.z) | ((unsigned)f2bf(f2.w) << 16);
    o1.z = (unsigned)f2bf(f3.x) | ((unsigned)f2bf(f3.y) << 16);
    o1.w = (unsigned)f2bf(f3.z) | ((unsigned)f2bf(f3.w) << 16);
    *(uint4*)aw = o0;
    *(uint4*)(aw + 8) = o1;
    __syncthreads();

    bf16x8 af[4], bfr[4];
#pragma unroll
    for (int i = 0; i < 4; ++i) {
      af[i] = *(const bf16x8*)(As + (w_m * 64 + i * 16 + l16) * 32 + q * 8);
      bfr[i] = *(const bf16x8*)(Bs + (w_n * 64 + i * 16 + l16) * 32 + q * 8);
    }
#pragma unroll
    for (int mi = 0; mi < 4; ++mi)
#pragma unroll
      for (int ni = 0; ni < 4; ++ni)
        acc[mi][ni] = __builtin_amdgcn_mfma_f32_16x16x32_bf16(af[mi], bfr[ni], acc[mi][ni], 0, 0, 0);
    __syncthreads();
  }

  float bval[4];
#pragma unroll
  for (int ni = 0; ni < 4; ++ni)
    bval[ni] = b1[(size_t)head * HID + n0 + w_n * 64 + ni * 16 + l16];
#pragma unroll
  for (int mi = 0; mi < 4; ++mi) {
#pragma unroll
    for (int r = 0; r < 4; ++r) {
      int m = w_m * 64 + mi * 16 + q * 4 + r;
      if (m < rows) {
        int p = row0 + m;
#pragma unroll
        for (int ni = 0; ni < 4; ++ni) {
          int n = n0 + w_n * 64 + ni * 16 + l16;
          float v = acc[mi][ni][r] + bval[ni];
          v = v > 0.f ? v : 0.f;
          Hb[(size_t)p * HID + n] = f2bf(v);
        }
      }
    }
  }
}

// one 128x128 GEMM2 tile: A = Hb (bf16), B = W2t, fp32 scatter to out
__device__ __forceinline__ void gemm2_tile(const unsigned short* __restrict__ Hb,
                                           const unsigned short* __restrict__ W2t,
                                           const float* __restrict__ b2,
                                           const int* __restrict__ order,
                                           float* __restrict__ out,
                                           int head, int row0, int rows, int n0,
                                           char* smem, int tid) {
  unsigned short* As = (unsigned short*)smem;
  unsigned short* Bs = (unsigned short*)(smem + 8192);
  int wave = tid >> 6, lane = tid & 63;
  int q = lane >> 4, l16 = lane & 15;
  int w_m = wave >> 1, w_n = wave & 1;
  int ldrow = lane >> 2, ldcol = (lane & 3) * 8;
  int c0 = wave * 2, c1 = c0 + 1;

  const unsigned short* Bh = W2t + (size_t)head * (size_t)OUT_F * HID;
  int ar0 = row0 + min(c0 * 16 + ldrow, rows - 1);
  int ar1 = row0 + min(c1 * 16 + ldrow, rows - 1);
  const unsigned short* ap0 = Hb + (size_t)ar0 * HID + ldcol;
  const unsigned short* ap1 = Hb + (size_t)ar1 * HID + ldcol;
  const unsigned short* bp0 = Bh + (size_t)(n0 + c0 * 16 + ldrow) * HID + ldcol;
  const unsigned short* bp1 = Bh + (size_t)(n0 + c1 * 16 + ldrow) * HID + ldcol;
  unsigned short* lA0 = As + c0 * 512;
  unsigned short* lA1 = As + c1 * 512;
  unsigned short* lB0 = Bs + c0 * 512;
  unsigned short* lB1 = Bs + c1 * 512;

  f32x4 acc[4][4];
#pragma unroll
  for (int i = 0; i < 4; ++i)
#pragma unroll
    for (int j = 0; j < 4; ++j) acc[i][j] = (f32x4){0.f, 0.f, 0.f, 0.f};

  for (int k0 = 0; k0 < HID; k0 += 32) {
    __builtin_amdgcn_global_load_lds((gu32*)ap0, (lu32*)lA0, 16, 0, 0);
    __builtin_amdgcn_global_load_lds((gu32*)ap1, (lu32*)lA1, 16, 0, 0);
    __builtin_amdgcn_global_load_lds((gu32*)bp0, (lu32*)lB0, 16, 0, 0);
    __builtin_amdgcn_global_load_lds((gu32*)bp1, (lu32*)lB1, 16, 0, 0);
    ap0 += 32; ap1 += 32; bp0 += 32; bp1 += 32;
    __syncthreads();

    bf16x8 af[4], bfr[4];
#pragma unroll
    for (int i = 0; i < 4; ++i) {
      af[i] = *(const bf16x8*)(As + (w_m * 64 + i * 16 + l16) * 32 + q * 8);
      bfr[i] = *(const bf16x8*)(Bs + (w_n * 64 + i * 16 + l16) * 32 + q * 8);
    }
#pragma unroll
    for (int mi = 0; mi < 4; ++mi)
#pragma unroll
      for (int ni = 0; ni < 4; ++ni)
        acc[mi][ni] = __builtin_amdgcn_mfma_f32_16x16x32_bf16(af[mi], bfr[ni], acc[mi][ni], 0, 0, 0);
    __syncthreads();
  }

  float bval[4];
#pragma unroll
  for (int ni = 0; ni < 4; ++ni)
    bval[ni] = b2[(size_t)head * OUT_F + n0 + w_n * 64 + ni * 16 + l16];
#pragma unroll
  for (int mi = 0; mi < 4; ++mi) {
#pragma unroll
    for (int r = 0; r < 4; ++r) {
      int m = w_m * 64 + mi * 16 + q * 4 + r;
      if (m < rows) {
        int rg = order[row0 + m];
#pragma unroll
        for (int ni = 0; ni < 4; ++ni) {
          int n = n0 + w_n * 64 + ni * 16 + l16;
          out[(size_t)rg * OUT_F + n] = acc[mi][ni][r] + bval[ni];
        }
      }
    }
  }
}

// ---------------- dispatch 1: bucket (block 0) || W1 transpose (blocks 1..256)
__global__ __launch_bounds__(256) void prep1_kernel(const int* __restrict__ idxh,
                                                    int* order, int* offsets,
                                                    const float* __restrict__ W1,
                                                    unsigned short* __restrict__ W1t) {
  __shared__ __align__(16) char smem[16640];
  int tid = threadIdx.x;
  int b = blockIdx.x;
  if (b == 0) {
    bucket_body(idxh, order, offsets, smem, tid);
  } else {
    transpose_one(W1, W1t, IN_F, HID, b - 1, HID / 64, smem, tid);
  }
}

// ---------------- dispatch 2: gemm1 (blocks 0..159) || W2 transpose (160..2207)
__global__ __launch_bounds__(256) void mid_kernel(const float* __restrict__ X,
                                                  const int* __restrict__ order,
                                                  const int* __restrict__ offsets,
                                                  const unsigned short* __restrict__ W1t,
                                                  const float* __restrict__ b1,
                                                  unsigned short* __restrict__ Hb,
                                                  const float* __restrict__ W2,
                                                  unsigned short* __restrict__ W2t) {
  __shared__ __align__(16) char smem[16640];
  int tid = threadIdx.x;
  int b = blockIdx.x;
  if (b < MT * 4) {
    int my = b >> 2, nx = b & 3;
    int head, row0, rows;
    if (!map_tile(offsets, my, head, row0, rows)) return;
    gemm1_tile(X, order, W1t, b1, Hb, head, row0, rows, nx * 128, smem, tid);
  } else {
    transpose_one(W2, W2t, HID, OUT_F, b - MT * 4, OUT_F / 64, smem, tid);
  }
}

// ---------------- dispatch 3: gemm2 ----------------------------------------
__global__ __launch_bounds__(256) void gemm2_kernel(const unsigned short* __restrict__ Hb,
                                                    const unsigned short* __restrict__ W2t,
                                                    const float* __restrict__ b2,
                                                    const int* __restrict__ offsets,
                                                    const int* __restrict__ order,
                                                    float* __restrict__ out) {
  __shared__ __align__(16) char smem[16384];
  int head, row0, rows;
  if (!map_tile(offsets, blockIdx.y, head, row0, rows)) return;
  gemm2_tile(Hb, W2t, b2, order, out, head, row0, rows, blockIdx.x * 128, smem, threadIdx.x);
}

extern "C" void kernel_launch(void* const* d_in, const int* in_sizes, int n_in,
                              void* d_out, int out_size, void* d_ws, size_t ws_size,
                              hipStream_t stream) {
  const float* X = (const float*)d_in[0];
  const int* idxh = (const int*)d_in[1];
  const float* W1 = (const float*)d_in[2];
  const float* b1 = (const float*)d_in[3];
  const float* W2 = (const float*)d_in[4];
  const float* b2 = (const float*)d_in[5];
  float* out = (float*)d_out;

  char* ws = (char*)d_ws;
  int* order = (int*)ws;                     ws += (size_t)BATCH * 4;
  int* offsets = (int*)ws;                   ws += 64;
  unsigned short* W1t = (unsigned short*)ws; ws += (size_t)N_HEADS * IN_F * HID * 2;
  unsigned short* W2t = (unsigned short*)ws; ws += (size_t)N_HEADS * HID * OUT_F * 2;
  unsigned short* Hb = (unsigned short*)ws;  ws += (size_t)BATCH * HID * 2;

  // d1: bucket || W1 transpose (256 tiles)
  prep1_kernel<<<dim3(1 + 256), dim3(256), 0, stream>>>(idxh, order, offsets, W1, W1t);
  // d2: gemm1 (160 tile-blocks, dispatched first) || W2 transpose (2048 tiles)
  mid_kernel<<<dim3(MT * 4 + 2048), dim3(256), 0, stream>>>(X, order, offsets, W1t, b1, Hb, W2, W2t);
  // d3: gemm2
  gemm2_kernel<<<dim3(OUT_F / 128, MT), dim3(256), 0, stream>>>(Hb, W2t, b2, offsets, order, out);
}